// Round 5
// baseline (740.476 us; speedup 1.0000x reference)
//
#include <hip/hip_runtime.h>
#include <stdint.h>

typedef unsigned short u16;
typedef unsigned int u32;
typedef __attribute__((ext_vector_type(8))) short short8v;   // 8 bf16 = 4 VGPRs
typedef __attribute__((ext_vector_type(4))) float f32x4;

#define NB 16      // batches per block -> 512 blocks of 16 waves -> 2 blocks/CU, 8 waves/SIMD
#define HISTN 64
#define TGEN 193   // L+1

// strides (elements)
#define S_NOISE 2048   // 256*8
#define S_HIST  192    // 64*3
#define S_GAP   386    // 193*2
#define S_OUT   771    // 257*3

// hst row: k0..63 h | k64 x0, k65 x1, k66 dp_hi, k67 dp_lo, k68 dist_hi,
// k69 dist_lo, k70 dist_hi(dup, pairs wdist_lo), k71 dp_hi(dup, pairs wdp_lo),
// k72..79 noise, k80..95 zero, k96..103 pad. 104 u16 = 208 B.
#define HROW 104

__device__ __forceinline__ float b2f(u16 u) { return __uint_as_float(((u32)u) << 16); }
__device__ __forceinline__ u16 f2b(float f) {
    u32 u = __float_as_uint(f);
    u32 r = (u + 0x7fffu + ((u >> 16) & 1u)) >> 16;
    return (u16)r;
}
// fast transcendentals: v_rcp_f32 (~1 ulp) instead of full-precision v_div
__device__ __forceinline__ float rcp_(float x) { return __builtin_amdgcn_rcpf(x); }
__device__ __forceinline__ float sigf(float x) { return rcp_(1.0f + __expf(-x)); }
__device__ __forceinline__ float tanhf_(float x) {
    return __builtin_fmaf(-2.0f, rcp_(1.0f + __expf(2.0f * x)), 1.0f);
}
__device__ __forceinline__ float ldv(const void* p, int idx, bool f32) {
    return f32 ? ((const float*)p)[idx] : b2f(((const u16*)p)[idx]);
}
// LDS-only barrier: drain LDS ops; global prefetch rides across (no vmcnt drain)
__device__ __forceinline__ void sync_lds() {
    asm volatile("s_waitcnt lgkmcnt(0)" ::: "memory");
    __builtin_amdgcn_s_barrier();
}

extern "C" __global__ void __launch_bounds__(1024, 8)
lstm_gen_kernel(const void* __restrict__ noise, const void* __restrict__ hist_x,
                const void* __restrict__ gap, const void* __restrict__ pW_ih,
                const void* __restrict__ pW_hh, const void* __restrict__ pb_ih,
                const void* __restrict__ pb_hh, const void* __restrict__ pW1,
                const void* __restrict__ pb1, const void* __restrict__ pW2,
                const void* __restrict__ pb2, void* __restrict__ out)
{
    __shared__ u16 hst[NB * HROW];     // 3328 B
    __shared__ float zpl[NB * 20];     // 1280 B

    const int tid = threadIdx.x;
    const int lane = tid & 63;
    const int w = tid >> 6;        // wave 0..15 -> owns units 4w..4w+3 (gate rows 16w..16w+15)
    const int lg = lane >> 4;      // k-group / C-row group
    const int ln = lane & 15;      // A-row / batch column

    // ---- dtype detection (proven logic) ----
    bool is_f32 = false;
    {
        const u32* p = (const u32*)pW_hh;
        for (int i = 0; i < 64; i++) {
            u32 v = p[i];
            float a = b2f((u16)(v & 0xffffu));
            float bb = b2f((u16)(v >> 16));
            if (!(fabsf(a) <= 0.5f) || !(fabsf(bb) <= 0.5f)) is_f32 = true;
        }
    }

    for (int i = tid; i < NB * HROW / 2; i += 1024) ((u32*)hst)[i] = 0u;

    // ---- persistent A fragments: ONE 16-row tile per wave, rows r' = j*4+g
    // (unit-major). A lane: row=ln -> unit j = 4w+(ln>>2), gate g = ln&3 ----
    short8v a0, a1, a2;
    {
        const int j = (w << 2) | (ln >> 2);
        const int g = ln & 3;
        const int row = (g << 6) | j;   // original weight row = gate*64 + unit
        float wdp = ldv(pW_ih, row * 12 + 2, is_f32);
        u16 wdph = f2b(wdp);
        u16 wdpl = f2b(wdp - b2f(wdph));
        float wds = ldv(pW_ih, row * 12 + 3, is_f32);
        u16 wdsh = f2b(wds);
        u16 wdsl = f2b(wds - b2f(wdsh));
#pragma unroll
        for (int e = 0; e < 8; e++) {
            const int c = lg * 8 + e;
            a0[e] = (short)f2b(ldv(pW_hh, row * 64 + c, is_f32));
            a1[e] = (short)f2b(ldv(pW_hh, row * 64 + 32 + c, is_f32));
            u16 v = 0;
            if (c == 0 || c == 1) v = f2b(ldv(pW_ih, row * 12 + c, is_f32));
            else if (c == 2 || c == 3) v = wdph;       // x dp_hi, dp_lo
            else if (c == 4 || c == 5) v = wdsh;       // x dist_hi, dist_lo
            else if (c == 6) v = wdsl;                 // x dist_hi (dup)
            else if (c == 7) v = wdpl;                 // x dp_hi (dup)
            else if (c >= 8 && c < 16) v = f2b(ldv(pW_ih, row * 12 + (c - 4), is_f32));
            a2[e] = (short)v;
        }
    }

    // C-side bias: rows r' = 16w + lg*4 + q
    f32x4 bias0;
    {
        const int jc = (w << 2) | lg;
#pragma unroll
        for (int q = 0; q < 4; q++) {
            const int row = (q << 6) | jc;
            bias0[q] = ldv(pb_ih, row, is_f32) + ldv(pb_hh, row, is_f32);
        }
    }

    // ---- MLP head fragments (waves 12..15 own W1 rows 16(w-12)..+16) ----
    const bool mlpw = (w >= 12);
    short8v w1F0 = {}, w1F1 = {};
    f32x4 b1v = {0.f, 0.f, 0.f, 0.f};
    float w2L[4] = {0.f, 0.f, 0.f, 0.f};
    if (mlpw) {
        const int wp = w - 12;
        const int row1 = (wp << 4) | ln;
#pragma unroll
        for (int e = 0; e < 8; e++) {
            w1F0[e] = (short)f2b(ldv(pW1, row1 * 64 + lg * 8 + e, is_f32));
            w1F1[e] = (short)f2b(ldv(pW1, row1 * 64 + 32 + lg * 8 + e, is_f32));
        }
        const int rq = (wp << 4) | (lg << 2);
#pragma unroll
        for (int q = 0; q < 4; q++) {
            b1v[q] = ldv(pb1, rq + q, is_f32);
            w2L[q] = ldv(pW2, rq + q, is_f32);
        }
    }

    // ---- owner lanes (tid<16, wave 0): per-batch scalar state + prefetch ----
    const bool owner = tid < NB;
    const size_t gb = (size_t)blockIdx.x * NB + (size_t)(tid & (NB - 1));
    const u16* nz_h = (const u16*)noise + gb * S_NOISE;
    const float* nz_f = (const float*)noise + gb * S_NOISE;
    const u16* hx_h = (const u16*)hist_x + gb * S_HIST;
    const float* hx_f = (const float*)hist_x + gb * S_HIST;
    const u16* gd_h = (const u16*)gap + gb * S_GAP;
    const float* gd_f = (const float*)gap + gb * S_GAP;
    u16* out_h = (u16*)out + gb * S_OUT;
    float* out_f = (float*)out + gb * S_OUT;

    float dist = 0.0f, b2v = 0.0f;
    float cv0 = 0.f, cv1 = 0.f, cv2 = 0.f;
    u32 n01 = 0, n23 = 0, n45 = 0, n67 = 0;

    auto ldnoise = [&](int t) {
        if (is_f32) {
            const float4* q = (const float4*)(nz_f + t * 8);
            float4 a = q[0], bq = q[1];
            n01 = (u32)f2b(a.x) | ((u32)f2b(a.y) << 16);
            n23 = (u32)f2b(a.z) | ((u32)f2b(a.w) << 16);
            n45 = (u32)f2b(bq.x) | ((u32)f2b(bq.y) << 16);
            n67 = (u32)f2b(bq.z) | ((u32)f2b(bq.w) << 16);
        } else {
            uint4 nv = *(const uint4*)(nz_h + t * 8);
            n01 = nv.x; n23 = nv.y; n45 = nv.z; n67 = nv.w;
        }
    };

    if (owner) {
        b2v = ldv(pb2, 0, is_f32);
        if (is_f32) { cv0 = hx_f[0]; cv1 = hx_f[1]; cv2 = hx_f[2]; }
        else { cv0 = b2f(hx_h[0]); cv1 = b2f(hx_h[1]); cv2 = b2f(hx_h[2]); }
        ldnoise(0);
    }

    float cst0 = 0.f;
    __syncthreads();

    // ================= conditioning: 64 steps =================
#pragma unroll 1
    for (int t = 0; t < HISTN; t++) {
        short8v bf0 = *(const short8v*)&hst[ln * HROW + lg * 8];
        short8v bf1 = *(const short8v*)&hst[ln * HROW + 32 + lg * 8];
        if (owner) {
            dist += cv2;
            u16 dph = f2b(cv2); u16 dpl = f2b(cv2 - b2f(dph));
            u16 dsh = f2b(dist); u16 dsl = f2b(dist - b2f(dsh));
            u16* hr = &hst[tid * HROW];
            *(u32*)&hr[64] = (u32)f2b(cv0) | ((u32)f2b(cv1) << 16);
            *(u32*)&hr[66] = (u32)dph | ((u32)dpl << 16);
            *(u32*)&hr[68] = (u32)dsh | ((u32)dsl << 16);
            *(u32*)&hr[70] = (u32)dsh | ((u32)dph << 16);
            *(u32*)&hr[72] = n01; *(u32*)&hr[74] = n23;
            *(u32*)&hr[76] = n45; *(u32*)&hr[78] = n67;
        }
        sync_lds();   // x visible
        if (owner) {  // out-write + prefetch overlap mfma below
            if (is_f32) { out_f[t*3] = cv0; out_f[t*3+1] = cv1; out_f[t*3+2] = cv2; }
            else { out_h[t*3] = f2b(cv0); out_h[t*3+1] = f2b(cv1); out_h[t*3+2] = f2b(cv2); }
            if (t + 1 < HISTN) {
                if (is_f32) { cv0 = hx_f[(t+1)*3]; cv1 = hx_f[(t+1)*3+1]; cv2 = hx_f[(t+1)*3+2]; }
                else { cv0 = b2f(hx_h[(t+1)*3]); cv1 = b2f(hx_h[(t+1)*3+1]); cv2 = b2f(hx_h[(t+1)*3+2]); }
                ldnoise(t + 1);
            } else {
                if (is_f32) { cv0 = gd_f[0]; cv1 = gd_f[1]; }
                else { u32 g = *(const u32*)gd_h; cv0 = b2f((u16)(g & 0xffffu)); cv1 = b2f((u16)(g >> 16)); }
                ldnoise(HISTN);
            }
        }
        short8v bf2 = *(const short8v*)&hst[ln * HROW + 64 + lg * 8];
        f32x4 acc0 = bias0;
        acc0 = __builtin_amdgcn_mfma_f32_16x16x32_bf16(a0, bf0, acc0, 0, 0, 0);
        acc0 = __builtin_amdgcn_mfma_f32_16x16x32_bf16(a1, bf1, acc0, 0, 0, 0);
        acc0 = __builtin_amdgcn_mfma_f32_16x16x32_bf16(a2, bf2, acc0, 0, 0, 0);
        float h0;
        { float iv = sigf(acc0[0]), fv = sigf(acc0[1]), gv = tanhf_(acc0[2]), ov = sigf(acc0[3]);
          cst0 = fv * cst0 + iv * gv; h0 = ov * tanhf_(cst0); }
        hst[ln * HROW + ((w << 2) | lg)] = f2b(h0);
        sync_lds();   // h visible
    }

    // ================= generation: 193 steps =================
#pragma unroll 1
    for (int tg = 0; tg < TGEN; tg++) {
        short8v bf0 = *(const short8v*)&hst[ln * HROW + lg * 8];
        short8v bf1 = *(const short8v*)&hst[ln * HROW + 32 + lg * 8];
        if (mlpw) {   // MLP head reuses the same h B-fragments
            f32x4 m0 = b1v;
            m0 = __builtin_amdgcn_mfma_f32_16x16x32_bf16(w1F0, bf0, m0, 0, 0, 0);
            m0 = __builtin_amdgcn_mfma_f32_16x16x32_bf16(w1F1, bf1, m0, 0, 0, 0);
            float p0 = w2L[0] * tanhf_(m0[0]) + w2L[1] * tanhf_(m0[1])
                     + w2L[2] * tanhf_(m0[2]) + w2L[3] * tanhf_(m0[3]);
            zpl[ln * 20 + (((w - 12) << 2) | lg)] = p0;
        }
        sync_lds();   // B1: partials visible
        if (owner) {
            const float4* zr = (const float4*)&zpl[tid * 20];
            float4 z0 = zr[0], z1 = zr[1], z2 = zr[2], z3 = zr[3];
            float pre2 = b2v + z0.x + z0.y + z0.z + z0.w + z1.x + z1.y + z1.z + z1.w
                       + z2.x + z2.y + z2.z + z2.w + z3.x + z3.y + z3.z + z3.w;
            float zz = tanhf_(pre2);
            float dp = 24.0f * zz;
            dist += dp;
            u16 dph = f2b(dp); u16 dpl = f2b(dp - b2f(dph));
            u16 dsh = f2b(dist); u16 dsl = f2b(dist - b2f(dsh));
            u16* hr = &hst[tid * HROW];
            *(u32*)&hr[64] = (u32)f2b(cv0) | ((u32)f2b(cv1) << 16);
            *(u32*)&hr[66] = (u32)dph | ((u32)dpl << 16);
            *(u32*)&hr[68] = (u32)dsh | ((u32)dsl << 16);
            *(u32*)&hr[70] = (u32)dsh | ((u32)dph << 16);
            *(u32*)&hr[72] = n01; *(u32*)&hr[74] = n23;
            *(u32*)&hr[76] = n45; *(u32*)&hr[78] = n67;
            const int to = HISTN + tg;
            if (is_f32) { out_f[to*3] = cv0; out_f[to*3+1] = cv1; out_f[to*3+2] = dp; }
            else { out_h[to*3] = f2b(cv0); out_h[to*3+1] = f2b(cv1); out_h[to*3+2] = f2b(dp); }
        }
        sync_lds();   // B2: x visible
        if (owner && tg + 1 < TGEN) {   // prefetch rides over LDS-only barriers
            if (is_f32) { cv0 = gd_f[(tg+1)*2]; cv1 = gd_f[(tg+1)*2+1]; }
            else { u32 g = *(const u32*)(gd_h + (tg+1)*2);
                   cv0 = b2f((u16)(g & 0xffffu)); cv1 = b2f((u16)(g >> 16)); }
            if (tg + 1 < TGEN - 1) ldnoise(HISTN + tg + 1);
            else { n01 = n23 = n45 = n67 = 0; }
        }
        short8v bf2 = *(const short8v*)&hst[ln * HROW + 64 + lg * 8];
        f32x4 acc0 = bias0;
        acc0 = __builtin_amdgcn_mfma_f32_16x16x32_bf16(a0, bf0, acc0, 0, 0, 0);
        acc0 = __builtin_amdgcn_mfma_f32_16x16x32_bf16(a1, bf1, acc0, 0, 0, 0);
        acc0 = __builtin_amdgcn_mfma_f32_16x16x32_bf16(a2, bf2, acc0, 0, 0, 0);
        float h0;
        { float iv = sigf(acc0[0]), fv = sigf(acc0[1]), gv = tanhf_(acc0[2]), ov = sigf(acc0[3]);
          cst0 = fv * cst0 + iv * gv; h0 = ov * tanhf_(cst0); }
        hst[ln * HROW + ((w << 2) | lg)] = f2b(h0);
        sync_lds();   // B3: h visible
    }
}

extern "C" void kernel_launch(void* const* d_in, const int* in_sizes, int n_in,
                              void* d_out, int out_size, void* d_ws, size_t ws_size,
                              hipStream_t stream) {
    (void)in_sizes; (void)n_in; (void)d_ws; (void)ws_size; (void)out_size;
    lstm_gen_kernel<<<512, 1024, 0, stream>>>(
        d_in[0], d_in[1], d_in[2], d_in[3], d_in[4], d_in[5],
        d_in[6], d_in[7], d_in[8], d_in[9], d_in[10], d_out);
}

// Round 6
// 479.158 us; speedup vs baseline: 1.5454x; 1.5454x over previous
//
#include <hip/hip_runtime.h>
#include <stdint.h>

typedef unsigned short u16;
typedef unsigned int u32;
typedef __attribute__((ext_vector_type(8))) short short8v;   // 8 bf16 = 4 VGPRs
typedef __attribute__((ext_vector_type(4))) float f32x4;

#define NB 16      // batches per block -> 512 blocks -> 2 blocks/CU
#define HISTN 64
#define TGEN 193   // L+1

// strides (elements)
#define S_NOISE 2048   // 256*8
#define S_HIST  192    // 64*3
#define S_GAP   386    // 193*2
#define S_OUT   771    // 257*3

// hst row: k0..63 h | k64 x0, k65 x1, k66 dp_hi, k67 dp_lo, k68 dist_hi,
// k69 dist_lo, k70 dist_hi(dup), k71 dp_hi(dup), k72..79 noise, k80..95 zero,
// k96..103 pad. 104 u16 = 208 B. (cond loop uses the hi/lo-in-MFMA trick;
// gen loop zeroes k66..71 in the B-fragment and adds dp/dist via fp32 FMA.)
#define HROW 104

__device__ __forceinline__ float b2f(u16 u) { return __uint_as_float(((u32)u) << 16); }
__device__ __forceinline__ u16 f2b(float f) {
    u32 u = __float_as_uint(f);
    u32 r = (u + 0x7fffu + ((u >> 16) & 1u)) >> 16;
    return (u16)r;
}
// fast transcendentals: v_rcp_f32 (~1 ulp) instead of full-precision v_div
__device__ __forceinline__ float rcp_(float x) { return __builtin_amdgcn_rcpf(x); }
__device__ __forceinline__ float sigf(float x) { return rcp_(1.0f + __expf(-x)); }
__device__ __forceinline__ float tanhf_(float x) {
    return __builtin_fmaf(-2.0f, rcp_(1.0f + __expf(2.0f * x)), 1.0f);
}
__device__ __forceinline__ float ldv(const void* p, int idx, bool f32) {
    return f32 ? ((const float*)p)[idx] : b2f(((const u16*)p)[idx]);
}
// LDS-only barrier: drain LDS ops; global prefetch rides across (no vmcnt drain)
__device__ __forceinline__ void sync_lds() {
    asm volatile("s_waitcnt lgkmcnt(0)" ::: "memory");
    __builtin_amdgcn_s_barrier();
}

extern "C" __global__ void __launch_bounds__(512, 4)
lstm_gen_kernel(const void* __restrict__ noise, const void* __restrict__ hist_x,
                const void* __restrict__ gap, const void* __restrict__ pW_ih,
                const void* __restrict__ pW_hh, const void* __restrict__ pb_ih,
                const void* __restrict__ pb_hh, const void* __restrict__ pW1,
                const void* __restrict__ pb1, const void* __restrict__ pW2,
                const void* __restrict__ pb2, void* __restrict__ out)
{
    __shared__ u16 hst[NB * HROW];           // 3328 B
    __shared__ float zpl[NB * 4];            // 256 B (4 wave-partials per batch)
    __shared__ float gds[TGEN][NB][2];       // staged gap, fp32-exact, 24704 B
    __shared__ u16 nring[32][NB][8];         // rolling bf16 noise ring, 8192 B
    __shared__ float dpd[NB];                // dist handoff cond->gen, 64 B

    const int tid = threadIdx.x;
    const int lane = tid & 63;
    const int w = tid >> 6;        // wave 0..7, owns gate-row tiles [16w,+16) and [128+16w,+16)
    const int lg = lane >> 4;      // k-group / C-row group
    const int ln = lane & 15;      // A-row / batch column

    // ---- dtype detection (proven logic) ----
    bool is_f32 = false;
    {
        const u32* p = (const u32*)pW_hh;
        for (int i = 0; i < 64; i++) {
            u32 v = p[i];
            float a = b2f((u16)(v & 0xffffu));
            float bb = b2f((u16)(v >> 16));
            if (!(fabsf(a) <= 0.5f) || !(fabsf(bb) <= 0.5f)) is_f32 = true;
        }
    }

    for (int i = tid; i < NB * HROW / 2; i += 512) ((u32*)hst)[i] = 0u;
    // stage gap as fp32 (exact pass-through for either input dtype)
    for (int i = tid; i < TGEN * NB * 2; i += 512) {
        int t = i >> 5, r = i & 31, b = r >> 1, k = r & 1;
        gds[t][b][k] = ldv(gap, ((size_t)blockIdx.x * NB + b) * S_GAP + t * 2 + k, is_f32);
    }

    // ---- persistent A fragments: two tiles per wave, rows r' = j*4+g ----
    short8v a00, a01, a02, a10, a11, a12;
#pragma unroll
    for (int T = 0; T < 2; T++) {
        const int j = (T << 5) | (w << 2) | (ln >> 2);
        const int g = ln & 3;
        const int row = (g << 6) | j;   // original weight row = gate*64 + unit
        float wdp = ldv(pW_ih, row * 12 + 2, is_f32);
        u16 wdph = f2b(wdp);
        u16 wdpl = f2b(wdp - b2f(wdph));
        float wds = ldv(pW_ih, row * 12 + 3, is_f32);
        u16 wdsh = f2b(wds);
        u16 wdsl = f2b(wds - b2f(wdsh));
        short8v f0, f1, f2;
#pragma unroll
        for (int e = 0; e < 8; e++) {
            const int c = lg * 8 + e;
            f0[e] = (short)f2b(ldv(pW_hh, row * 64 + c, is_f32));
            f1[e] = (short)f2b(ldv(pW_hh, row * 64 + 32 + c, is_f32));
            u16 v = 0;
            if (c == 0 || c == 1) v = f2b(ldv(pW_ih, row * 12 + c, is_f32));
            else if (c == 2 || c == 3) v = wdph;       // cond: x dp_hi, dp_lo
            else if (c == 4 || c == 5) v = wdsh;       // cond: x dist_hi, dist_lo
            else if (c == 6) v = wdsl;                 // cond: x dist_hi (dup)
            else if (c == 7) v = wdpl;                 // cond: x dp_hi (dup)
            else if (c >= 8 && c < 16) v = f2b(ldv(pW_ih, row * 12 + (c - 4), is_f32));
            f2[e] = (short)v;
        }
        if (T == 0) { a00 = f0; a01 = f1; a02 = f2; }
        else        { a10 = f0; a11 = f1; a12 = f2; }
    }

    // C-side: bias + dp/dist weight columns (fp32 path, used in gen only)
    f32x4 bias0, bias1, wd0, wd1, ws0, ws1;
#pragma unroll
    for (int T = 0; T < 2; T++) {
        const int jc = (T << 5) | (w << 2) | lg;
        f32x4 bv, dv, sv;
#pragma unroll
        for (int q = 0; q < 4; q++) {
            const int row = (q << 6) | jc;
            bv[q] = ldv(pb_ih, row, is_f32) + ldv(pb_hh, row, is_f32);
            dv[q] = ldv(pW_ih, row * 12 + 2, is_f32);
            sv[q] = ldv(pW_ih, row * 12 + 3, is_f32);
        }
        if (T == 0) { bias0 = bv; wd0 = dv; ws0 = sv; }
        else        { bias1 = bv; wd1 = dv; ws1 = sv; }
    }

    // ---- MLP head fragments (waves 4..7 own W1 rows 16(w-4)..+16) ----
    const bool mlpw = (w >= 4);
    short8v w1F0 = {}, w1F1 = {};
    f32x4 b1v = {0.f, 0.f, 0.f, 0.f};
    float w2L[4] = {0.f, 0.f, 0.f, 0.f};
    if (mlpw) {
        const int wp = w - 4;
        const int row1 = (wp << 4) | ln;
#pragma unroll
        for (int e = 0; e < 8; e++) {
            w1F0[e] = (short)f2b(ldv(pW1, row1 * 64 + lg * 8 + e, is_f32));
            w1F1[e] = (short)f2b(ldv(pW1, row1 * 64 + 32 + lg * 8 + e, is_f32));
        }
        const int rq = (wp << 4) | (lg << 2);
#pragma unroll
        for (int q = 0; q < 4; q++) {
            b1v[q] = ldv(pb1, rq + q, is_f32);
            w2L[q] = ldv(pW2, rq + q, is_f32);
        }
    }

    const float b2v = ldv(pb2, 0, is_f32);

    // ---- owner lanes (tid<16): cond-phase per-batch state + prefetch ----
    const bool owner = tid < NB;
    const size_t gb = (size_t)blockIdx.x * NB + (size_t)(tid & (NB - 1));
    const u16* nz_h = (const u16*)noise + gb * S_NOISE;
    const float* nz_f = (const float*)noise + gb * S_NOISE;
    const u16* hx_h = (const u16*)hist_x + gb * S_HIST;
    const float* hx_f = (const float*)hist_x + gb * S_HIST;
    u16* out_h = (u16*)out + gb * S_OUT;
    float* out_f = (float*)out + gb * S_OUT;

    float dist = 0.0f;
    float cv0 = 0.f, cv1 = 0.f, cv2 = 0.f;
    u32 n01 = 0, n23 = 0, n45 = 0, n67 = 0;

    auto ldnoise = [&](int t) {
        if (is_f32) {
            const float4* q = (const float4*)(nz_f + t * 8);
            float4 a = q[0], bq = q[1];
            n01 = (u32)f2b(a.x) | ((u32)f2b(a.y) << 16);
            n23 = (u32)f2b(a.z) | ((u32)f2b(a.w) << 16);
            n45 = (u32)f2b(bq.x) | ((u32)f2b(bq.y) << 16);
            n67 = (u32)f2b(bq.z) | ((u32)f2b(bq.w) << 16);
        } else {
            uint4 nv = *(const uint4*)(nz_h + t * 8);
            n01 = nv.x; n23 = nv.y; n45 = nv.z; n67 = nv.w;
        }
    };

    if (owner) {
        if (is_f32) { cv0 = hx_f[0]; cv1 = hx_f[1]; cv2 = hx_f[2]; }
        else { cv0 = b2f(hx_h[0]); cv1 = b2f(hx_h[1]); cv2 = b2f(hx_h[2]); }
        ldnoise(0);
    }

    float cst0 = 0.f, cst1 = 0.f;
    __syncthreads();

    // ================= conditioning: 64 steps (R3-proven structure) =================
#pragma unroll 1
    for (int t = 0; t < HISTN; t++) {
        short8v bf0 = *(const short8v*)&hst[ln * HROW + lg * 8];
        short8v bf1 = *(const short8v*)&hst[ln * HROW + 32 + lg * 8];
        if (owner) {
            dist += cv2;
            u16 dph = f2b(cv2); u16 dpl = f2b(cv2 - b2f(dph));
            u16 dsh = f2b(dist); u16 dsl = f2b(dist - b2f(dsh));
            u16* hr = &hst[tid * HROW];
            *(u32*)&hr[64] = (u32)f2b(cv0) | ((u32)f2b(cv1) << 16);
            *(u32*)&hr[66] = (u32)dph | ((u32)dpl << 16);
            *(u32*)&hr[68] = (u32)dsh | ((u32)dsl << 16);
            *(u32*)&hr[70] = (u32)dsh | ((u32)dph << 16);
            *(u32*)&hr[72] = n01; *(u32*)&hr[74] = n23;
            *(u32*)&hr[76] = n45; *(u32*)&hr[78] = n67;
        }
        sync_lds();   // x visible
        if (owner) {  // out-write + prefetch overlap mfma below
            if (is_f32) { out_f[t*3] = cv0; out_f[t*3+1] = cv1; out_f[t*3+2] = cv2; }
            else { out_h[t*3] = f2b(cv0); out_h[t*3+1] = f2b(cv1); out_h[t*3+2] = f2b(cv2); }
            if (t + 1 < HISTN) {
                if (is_f32) { cv0 = hx_f[(t+1)*3]; cv1 = hx_f[(t+1)*3+1]; cv2 = hx_f[(t+1)*3+2]; }
                else { cv0 = b2f(hx_h[(t+1)*3]); cv1 = b2f(hx_h[(t+1)*3+1]); cv2 = b2f(hx_h[(t+1)*3+2]); }
                ldnoise(t + 1);
            }
        }
        short8v bf2 = *(const short8v*)&hst[ln * HROW + 64 + lg * 8];
        f32x4 acc0 = bias0, acc1 = bias1;
        acc0 = __builtin_amdgcn_mfma_f32_16x16x32_bf16(a00, bf0, acc0, 0, 0, 0);
        acc0 = __builtin_amdgcn_mfma_f32_16x16x32_bf16(a01, bf1, acc0, 0, 0, 0);
        acc0 = __builtin_amdgcn_mfma_f32_16x16x32_bf16(a02, bf2, acc0, 0, 0, 0);
        acc1 = __builtin_amdgcn_mfma_f32_16x16x32_bf16(a10, bf0, acc1, 0, 0, 0);
        acc1 = __builtin_amdgcn_mfma_f32_16x16x32_bf16(a11, bf1, acc1, 0, 0, 0);
        acc1 = __builtin_amdgcn_mfma_f32_16x16x32_bf16(a12, bf2, acc1, 0, 0, 0);
        float h0, h1;
        { float iv = sigf(acc0[0]), fv = sigf(acc0[1]), gv = tanhf_(acc0[2]), ov = sigf(acc0[3]);
          cst0 = fv * cst0 + iv * gv; h0 = ov * tanhf_(cst0); }
        { float iv = sigf(acc1[0]), fv = sigf(acc1[1]), gv = tanhf_(acc1[2]), ov = sigf(acc1[3]);
          cst1 = fv * cst1 + iv * gv; h1 = ov * tanhf_(cst1); }
        const int j0 = (w << 2) | lg;
        hst[ln * HROW + j0] = f2b(h0);
        hst[ln * HROW + j0 + 32] = f2b(h1);
        sync_lds();   // h visible
    }

    // ---- cond -> gen handoff: dist broadcast + initial noise ring fill ----
    if (owner) dpd[tid] = dist;
    {
        const int s = tid >> 4, b = tid & 15;   // 32 slots x 16 batches = 512 lanes
        const int t = HISTN + s;                // 64..95, all valid
        u32 r0, r1, r2, r3;
        if (is_f32) {
            const float* nf = (const float*)noise + ((size_t)blockIdx.x * NB + b) * S_NOISE + t * 8;
            float4 a = *(const float4*)nf, bq = *(const float4*)(nf + 4);
            r0 = (u32)f2b(a.x) | ((u32)f2b(a.y) << 16);
            r1 = (u32)f2b(a.z) | ((u32)f2b(a.w) << 16);
            r2 = (u32)f2b(bq.x) | ((u32)f2b(bq.y) << 16);
            r3 = (u32)f2b(bq.z) | ((u32)f2b(bq.w) << 16);
        } else {
            uint4 nv = *(const uint4*)((const u16*)noise + ((size_t)blockIdx.x * NB + b) * S_NOISE + t * 8);
            r0 = nv.x; r1 = nv.y; r2 = nv.z; r3 = nv.w;
        }
        u32* dst = (u32*)&nring[s][b][0];
        dst[0] = r0; dst[1] = r1; dst[2] = r2; dst[3] = r3;
    }
    sync_lds();
    dist = dpd[ln];   // every lane now tracks its batch's dist (replicated fp32)

    // ================= generation: 193 steps, TWO barriers, no serial phase ========
#pragma unroll 1
    for (int tg = 0; tg < TGEN; tg++) {
        // ---- P1: everything that doesn't need dp/dist ----
        short8v bf0 = *(const short8v*)&hst[ln * HROW + lg * 8];
        short8v bf1 = *(const short8v*)&hst[ln * HROW + 32 + lg * 8];
        float2 g2 = *(const float2*)&gds[tg][ln][0];
        short8v bf2 = {};
        if (lg == 0) { bf2[0] = (short)f2b(g2.x); bf2[1] = (short)f2b(g2.y); }
        else if (lg == 1) {
            union { uint4 u; short8v s; } cvt;
            cvt.u = *(const uint4*)&nring[tg & 31][ln][0];
            bf2 = cvt.s;
        }
        f32x4 acc0 = bias0, acc1 = bias1;
        acc0 = __builtin_amdgcn_mfma_f32_16x16x32_bf16(a00, bf0, acc0, 0, 0, 0);
        acc0 = __builtin_amdgcn_mfma_f32_16x16x32_bf16(a01, bf1, acc0, 0, 0, 0);
        acc0 = __builtin_amdgcn_mfma_f32_16x16x32_bf16(a02, bf2, acc0, 0, 0, 0);
        acc1 = __builtin_amdgcn_mfma_f32_16x16x32_bf16(a10, bf0, acc1, 0, 0, 0);
        acc1 = __builtin_amdgcn_mfma_f32_16x16x32_bf16(a11, bf1, acc1, 0, 0, 0);
        acc1 = __builtin_amdgcn_mfma_f32_16x16x32_bf16(a12, bf2, acc1, 0, 0, 0);
        if (mlpw) {   // MLP head on h_{t-1}; in-wave reduce over the 4 lg groups
            f32x4 m0 = b1v;
            m0 = __builtin_amdgcn_mfma_f32_16x16x32_bf16(w1F0, bf0, m0, 0, 0, 0);
            m0 = __builtin_amdgcn_mfma_f32_16x16x32_bf16(w1F1, bf1, m0, 0, 0, 0);
            float p = w2L[0] * tanhf_(m0[0]) + w2L[1] * tanhf_(m0[1])
                    + w2L[2] * tanhf_(m0[2]) + w2L[3] * tanhf_(m0[3]);
            p += __shfl_xor(p, 16);
            p += __shfl_xor(p, 32);
            if (lg == 0) zpl[(ln << 2) | (w - 4)] = p;
        }
        // rolling ring refill: once per 16 steps, slots for tg+16..tg+31
        if (((tg & 15) == 0) && tg > 0 && tg <= 176 && tid < 256) {
            const int s = tid >> 4, b = tid & 15;
            const int t = HISTN + tg + 16 + s;
            u32 r0 = 0, r1 = 0, r2 = 0, r3 = 0;
            if (t < 256) {
                if (is_f32) {
                    const float* nf = (const float*)noise + ((size_t)blockIdx.x * NB + b) * S_NOISE + t * 8;
                    float4 a = *(const float4*)nf, bq = *(const float4*)(nf + 4);
                    r0 = (u32)f2b(a.x) | ((u32)f2b(a.y) << 16);
                    r1 = (u32)f2b(a.z) | ((u32)f2b(a.w) << 16);
                    r2 = (u32)f2b(bq.x) | ((u32)f2b(bq.y) << 16);
                    r3 = (u32)f2b(bq.z) | ((u32)f2b(bq.w) << 16);
                } else {
                    uint4 nv = *(const uint4*)((const u16*)noise + ((size_t)blockIdx.x * NB + b) * S_NOISE + t * 8);
                    r0 = nv.x; r1 = nv.y; r2 = nv.z; r3 = nv.w;
                }
            }
            u32* dst = (u32*)&nring[(tg + 16 + s) & 31][b][0];
            dst[0] = r0; dst[1] = r1; dst[2] = r2; dst[3] = r3;
        }
        sync_lds();   // B1: zpl (and h reads complete)
        // ---- P2: head finish (replicated, bit-identical per batch) + gates ----
        f32x4 zr = *(const f32x4*)&zpl[ln << 2];
        float dp = 24.0f * tanhf_(b2v + zr[0] + zr[1] + zr[2] + zr[3]);
        dist += dp;
#pragma unroll
        for (int q = 0; q < 4; q++) {
            acc0[q] += wd0[q] * dp + ws0[q] * dist;
            acc1[q] += wd1[q] * dp + ws1[q] * dist;
        }
        float h0, h1;
        { float iv = sigf(acc0[0]), fv = sigf(acc0[1]), gv = tanhf_(acc0[2]), ov = sigf(acc0[3]);
          cst0 = fv * cst0 + iv * gv; h0 = ov * tanhf_(cst0); }
        { float iv = sigf(acc1[0]), fv = sigf(acc1[1]), gv = tanhf_(acc1[2]), ov = sigf(acc1[3]);
          cst1 = fv * cst1 + iv * gv; h1 = ov * tanhf_(cst1); }
        const int j0 = (w << 2) | lg;
        hst[ln * HROW + j0] = f2b(h0);
        hst[ln * HROW + j0 + 32] = f2b(h1);
        if (tid < NB) {
            const int to = HISTN + tg;
            if (is_f32) { out_f[to*3] = g2.x; out_f[to*3+1] = g2.y; out_f[to*3+2] = dp; }
            else { out_h[to*3] = f2b(g2.x); out_h[to*3+1] = f2b(g2.y); out_h[to*3+2] = f2b(dp); }
        }
        sync_lds();   // B2: h_t visible
    }
}

extern "C" void kernel_launch(void* const* d_in, const int* in_sizes, int n_in,
                              void* d_out, int out_size, void* d_ws, size_t ws_size,
                              hipStream_t stream) {
    (void)in_sizes; (void)n_in; (void)d_ws; (void)ws_size; (void)out_size;
    lstm_gen_kernel<<<512, 512, 0, stream>>>(
        d_in[0], d_in[1], d_in[2], d_in[3], d_in[4], d_in[5],
        d_in[6], d_in[7], d_in[8], d_in[9], d_in[10], d_out);
}

// Round 7
// 435.778 us; speedup vs baseline: 1.6992x; 1.0995x over previous
//
#include <hip/hip_runtime.h>
#include <stdint.h>

typedef unsigned short u16;
typedef unsigned int u32;
typedef __attribute__((ext_vector_type(8))) short short8v;   // 8 bf16 = 4 VGPRs
typedef __attribute__((ext_vector_type(4))) float f32x4;

#define NB 16      // batches per block -> 512 blocks -> 2 blocks/CU
#define HISTN 64
#define TGEN 193   // L+1

// strides (elements)
#define S_NOISE 2048   // 256*8
#define S_HIST  192    // 64*3
#define S_GAP   386    // 193*2
#define S_OUT   771    // 257*3

#define HROW 104       // h row stride (u16): proven bank-uniform for b128 reads
#define L2E  1.442695041f
#define L2E2 2.885390082f

__device__ __forceinline__ float b2f(u16 u) { return __uint_as_float(((u32)u) << 16); }
__device__ __forceinline__ u16 f2b(float f) {
    u32 u = __float_as_uint(f);
    u32 r = (u + 0x7fffu + ((u >> 16) & 1u)) >> 16;
    return (u16)r;
}
__device__ __forceinline__ float rcp_(float x) { return __builtin_amdgcn_rcpf(x); }
__device__ __forceinline__ float ex2(float x) { return __builtin_amdgcn_exp2f(x); }
// pack 2 f32 -> 2 bf16 (RNE); lo = a, hi = b
__device__ __forceinline__ u32 cvtpk(float a, float b) {
    u32 r; asm("v_cvt_pk_bf16_f32 %0, %1, %2" : "=v"(r) : "v"(a), "v"(b)); return r;
}
// tanh from prescaled arg s = 2*log2e*x  (NaN-safe at saturation)
__device__ __forceinline__ float tanh2(float s) {
    return __builtin_fmaf(-2.0f, rcp_(1.0f + ex2(s)), 1.0f);
}
// LSTM gate epilogue on prescaled pre-acts: a0,a1,a3 = -log2e*pre(i,f,o), a2 = 2log2e*pre(g)
__device__ __forceinline__ float cellh(const f32x4 a, float& c) {
    float iv = rcp_(1.0f + ex2(a[0]));
    float fv = rcp_(1.0f + ex2(a[1]));
    float gv = tanh2(a[2]);
    float ov = rcp_(1.0f + ex2(a[3]));
    c = __builtin_fmaf(fv, c, iv * gv);
    return ov * tanh2(L2E2 * c);
}
__device__ __forceinline__ float ldv(const void* p, int idx, bool f32) {
    return f32 ? ((const float*)p)[idx] : b2f(((const u16*)p)[idx]);
}
// LDS-only barrier: drain LDS ops; global prefetch rides across (no vmcnt drain)
__device__ __forceinline__ void sync_lds() {
    asm volatile("s_waitcnt lgkmcnt(0)" ::: "memory");
    __builtin_amdgcn_s_barrier();
}

extern "C" __global__ void __launch_bounds__(512, 4)
lstm_gen_kernel(const void* __restrict__ noise, const void* __restrict__ hist_x,
                const void* __restrict__ gap, const void* __restrict__ pW_ih,
                const void* __restrict__ pW_hh, const void* __restrict__ pb_ih,
                const void* __restrict__ pb_hh, const void* __restrict__ pW1,
                const void* __restrict__ pb1, const void* __restrict__ pW2,
                const void* __restrict__ pb2, void* __restrict__ out)
{
    __shared__ u16 hb[2][NB * HROW];       // double-buffered h, 6656 B
    __shared__ u16 cxsA[HISTN][NB][8];     // cond x: x0,x1,dph,dpl,dsh,dsl,dsh,dph  16384 B
    __shared__ u16 cxsB[HISTN][NB][8];     // cond noise bf16                         16384 B
    __shared__ u32 gdsb[TGEN * NB];        // gap bf16-packed (prestage: hist fp32)   12352 B
    __shared__ u16 nring[32][NB][8];       // rolling gen-noise ring                   8192 B
    __shared__ float zpl[NB * 4];          // MLP per-wave partials                     256 B
    __shared__ float dpd[NB];              // dist handoff cond->gen                     64 B

    const int tid = threadIdx.x;
    const int lane = tid & 63;
    const int w = tid >> 6;        // wave 0..7; owns gate-row tiles [16w,+16) and [128+16w,+16)
    const int lg = lane >> 4;      // k-group / C-row group
    const int ln = lane & 15;      // A-row / batch column

    // ---- dtype detection (proven logic) ----
    bool is_f32 = false;
    {
        const u32* p = (const u32*)pW_hh;
        for (int i = 0; i < 64; i++) {
            u32 v = p[i];
            float a = b2f((u16)(v & 0xffffu));
            float bb = b2f((u16)(v >> 16));
            if (!(fabsf(a) <= 0.5f) || !(fabsf(bb) <= 0.5f)) is_f32 = true;
        }
    }

    float* hs = (float*)gdsb;   // prestage scratch: hist fp32 (3072 floats <= 12352 B)

    // ======== prestage phase 1: zero h, stage hist fp32, cond-noise bf16,
    //          initial gen-noise ring, hist->out copy ========
    for (int i = tid; i < NB * HROW; i += 512) ((u32*)hb)[i] = 0u;   // both buffers
    for (int i = tid; i < HISTN * NB * 3; i += 512) {
        int t = i / 48, r = i % 48, b = r / 3, k = r % 3;
        hs[i] = ldv(hist_x, ((size_t)blockIdx.x * NB + b) * S_HIST + t * 3 + k, is_f32);
    }
    for (int i = tid; i < HISTN * NB * 4; i += 512) {
        int t = i >> 6, r = i & 63, b = r >> 2, q = r & 3;
        size_t base = ((size_t)blockIdx.x * NB + b) * S_NOISE + t * 8;
        u32 v;
        if (is_f32) {
            const float* p = (const float*)noise + base + q * 2;
            v = (u32)f2b(p[0]) | ((u32)f2b(p[1]) << 16);
        } else v = ((const u32*)noise)[(base >> 1) + q];
        ((u32*)&cxsB[t][b][0])[q] = v;
    }
    {   // nring init: gen-noise t = 64..95
        const int s = tid >> 4, b = tid & 15;
        size_t base = ((size_t)blockIdx.x * NB + b) * S_NOISE + (size_t)(HISTN + s) * 8;
        u32 r0, r1, r2, r3;
        if (is_f32) {
            const float* nf = (const float*)noise + base;
            float4 a = *(const float4*)nf, bq = *(const float4*)(nf + 4);
            r0 = (u32)f2b(a.x) | ((u32)f2b(a.y) << 16);
            r1 = (u32)f2b(a.z) | ((u32)f2b(a.w) << 16);
            r2 = (u32)f2b(bq.x) | ((u32)f2b(bq.y) << 16);
            r3 = (u32)f2b(bq.z) | ((u32)f2b(bq.w) << 16);
        } else {
            uint4 nv = *(const uint4*)((const u16*)noise + base);
            r0 = nv.x; r1 = nv.y; r2 = nv.z; r3 = nv.w;
        }
        u32* dst = (u32*)&nring[s][b][0];
        dst[0] = r0; dst[1] = r1; dst[2] = r2; dst[3] = r3;
    }
    for (int i = tid; i < NB * HISTN * 3; i += 512) {   // exact hist -> out copy
        int b = i / 192, e = i % 192;
        size_t bt = (size_t)blockIdx.x * NB + b;
        if (is_f32) ((float*)out)[bt * S_OUT + e] = ((const float*)hist_x)[bt * S_HIST + e];
        else ((u16*)out)[bt * S_OUT + e] = ((const u16*)hist_x)[bt * S_HIST + e];
    }
    __syncthreads();

    // ======== prestage phase 2: per-batch cumsum + cond-x pack (16 lanes) ========
    if (tid < NB) {
        float dd = 0.0f;
#pragma unroll 1
        for (int t = 0; t < HISTN; t++) {
            float x0 = hs[t * 48 + tid * 3 + 0];
            float x1 = hs[t * 48 + tid * 3 + 1];
            float x2 = hs[t * 48 + tid * 3 + 2];
            dd += x2;
            u16 dph = f2b(x2); u16 dpl = f2b(x2 - b2f(dph));
            u16 dsh = f2b(dd); u16 dsl = f2b(dd - b2f(dsh));
            u32* dst = (u32*)&cxsA[t][tid][0];
            dst[0] = (u32)f2b(x0) | ((u32)f2b(x1) << 16);
            dst[1] = (u32)dph | ((u32)dpl << 16);
            dst[2] = (u32)dsh | ((u32)dsl << 16);
            dst[3] = (u32)dsh | ((u32)dph << 16);
        }
        dpd[tid] = dd;
    }
    __syncthreads();

    // ======== prestage phase 3: gap bf16-packed (overwrites hs scratch) ========
    for (int i = tid; i < TGEN * NB; i += 512) {
        int t = i >> 4, b = i & 15;
        size_t base = ((size_t)blockIdx.x * NB + b) * S_GAP + t * 2;
        u32 v;
        if (is_f32) {
            const float* p = (const float*)gap + base;
            v = (u32)f2b(p[0]) | ((u32)f2b(p[1]) << 16);
        } else v = *(const u32*)((const u16*)gap + base);
        gdsb[i] = v;
    }

    // ---- persistent A fragments, PRESCALED: rows i,f,o x -log2e; g x 2log2e ----
    short8v a00, a01, a02, a10, a11, a12;
#pragma unroll
    for (int T = 0; T < 2; T++) {
        const int j = (T << 5) | (w << 2) | (ln >> 2);
        const int g = ln & 3;
        const int row = (g << 6) | j;
        const float rs = (g == 2) ? L2E2 : -L2E;
        float wdp = ldv(pW_ih, row * 12 + 2, is_f32) * rs;
        u16 wdph = f2b(wdp); u16 wdpl = f2b(wdp - b2f(wdph));
        float wds = ldv(pW_ih, row * 12 + 3, is_f32) * rs;
        u16 wdsh = f2b(wds); u16 wdsl = f2b(wds - b2f(wdsh));
        short8v f0, f1, f2;
#pragma unroll
        for (int e = 0; e < 8; e++) {
            const int c = lg * 8 + e;
            f0[e] = (short)f2b(ldv(pW_hh, row * 64 + c, is_f32) * rs);
            f1[e] = (short)f2b(ldv(pW_hh, row * 64 + 32 + c, is_f32) * rs);
            u16 v = 0;
            if (c == 0 || c == 1) v = f2b(ldv(pW_ih, row * 12 + c, is_f32) * rs);
            else if (c == 2 || c == 3) v = wdph;
            else if (c == 4 || c == 5) v = wdsh;
            else if (c == 6) v = wdsl;
            else if (c == 7) v = wdpl;
            else if (c >= 8 && c < 16) v = f2b(ldv(pW_ih, row * 12 + (c - 4), is_f32) * rs);
            f2[e] = (short)v;
        }
        if (T == 0) { a00 = f0; a01 = f1; a02 = f2; }
        else        { a10 = f0; a11 = f1; a12 = f2; }
    }

    // C-side: prescaled bias + dp/dist weight columns (gen P2 fp32 path)
    f32x4 bias0, bias1, wd0, wd1, ws0, ws1;
#pragma unroll
    for (int T = 0; T < 2; T++) {
        const int jc = (T << 5) | (w << 2) | lg;
        f32x4 bv, dv, sv;
#pragma unroll
        for (int q = 0; q < 4; q++) {
            const int row = (q << 6) | jc;
            const float qs = (q == 2) ? L2E2 : -L2E;
            bv[q] = (ldv(pb_ih, row, is_f32) + ldv(pb_hh, row, is_f32)) * qs;
            dv[q] = ldv(pW_ih, row * 12 + 2, is_f32) * qs;
            sv[q] = ldv(pW_ih, row * 12 + 3, is_f32) * qs;
        }
        if (T == 0) { bias0 = bv; wd0 = dv; ws0 = sv; }
        else        { bias1 = bv; wd1 = dv; ws1 = sv; }
    }

    // ---- MLP head fragments (waves 4..7), W1/b1 x 2log2e; w2/b2 x 2log2e ----
    const bool mlpw = (w >= 4);
    short8v w1F0 = {}, w1F1 = {};
    f32x4 b1v = {0.f, 0.f, 0.f, 0.f};
    float w2L[4] = {0.f, 0.f, 0.f, 0.f};
    if (mlpw) {
        const int wp = w - 4;
        const int row1 = (wp << 4) | ln;
#pragma unroll
        for (int e = 0; e < 8; e++) {
            w1F0[e] = (short)f2b(ldv(pW1, row1 * 64 + lg * 8 + e, is_f32) * L2E2);
            w1F1[e] = (short)f2b(ldv(pW1, row1 * 64 + 32 + lg * 8 + e, is_f32) * L2E2);
        }
        const int rq = (wp << 4) | (lg << 2);
#pragma unroll
        for (int q = 0; q < 4; q++) {
            b1v[q] = ldv(pb1, rq + q, is_f32) * L2E2;
            w2L[q] = ldv(pW2, rq + q, is_f32) * L2E2;
        }
    }
    const float b2vs = ldv(pb2, 0, is_f32) * L2E2;

    // per-lane batch pointers (batch = ln)
    const size_t gb = (size_t)blockIdx.x * NB + (size_t)ln;
    const float* gd_f = (const float*)gap + gb * S_GAP;
    u16* out_h = (u16*)out + gb * S_OUT;
    float* out_f = (float*)out + gb * S_OUT;

    float cst0 = 0.f, cst1 = 0.f;
    int pc = 0;
    __syncthreads();   // gdsb + fragments ready

    // ================= conditioning: 64 steps, ONE barrier each =================
#pragma unroll 1
    for (int t = 0; t < HISTN; t++) {
        const u16* hc = hb[pc];
        u16* hn = hb[pc ^ 1];
        short8v bf0 = *(const short8v*)&hc[ln * HROW + lg * 8];
        short8v bf1 = *(const short8v*)&hc[ln * HROW + 32 + lg * 8];
        short8v bf2 = {};
        if (lg == 0) bf2 = *(const short8v*)&cxsA[t][ln][0];
        else if (lg == 1) bf2 = *(const short8v*)&cxsB[t][ln][0];
        f32x4 acc0 = bias0, acc1 = bias1;
        acc0 = __builtin_amdgcn_mfma_f32_16x16x32_bf16(a00, bf0, acc0, 0, 0, 0);
        acc0 = __builtin_amdgcn_mfma_f32_16x16x32_bf16(a01, bf1, acc0, 0, 0, 0);
        acc0 = __builtin_amdgcn_mfma_f32_16x16x32_bf16(a02, bf2, acc0, 0, 0, 0);
        acc1 = __builtin_amdgcn_mfma_f32_16x16x32_bf16(a10, bf0, acc1, 0, 0, 0);
        acc1 = __builtin_amdgcn_mfma_f32_16x16x32_bf16(a11, bf1, acc1, 0, 0, 0);
        acc1 = __builtin_amdgcn_mfma_f32_16x16x32_bf16(a12, bf2, acc1, 0, 0, 0);
        float h0 = cellh(acc0, cst0);
        float h1 = cellh(acc1, cst1);
        u32 hp = cvtpk(h0, h1);
        const int j0 = (w << 2) | lg;
        hn[ln * HROW + j0] = (u16)hp;
        hn[ln * HROW + j0 + 32] = (u16)(hp >> 16);
        sync_lds();
        pc ^= 1;
    }
    // pc == 0 here; final h lives in hb[0]

    float dist = dpd[ln];          // replicated per-batch dist after cumsum
    float gdf0 = 0.f, gdf1 = 0.f;  // writer fp32 gd prefetch (exact out path)
    if (is_f32 && tid < NB) { gdf0 = gd_f[0]; gdf1 = gd_f[1]; }

    // ================= generation: 193 steps, TWO barriers =================
#pragma unroll 1
    for (int tg = 0; tg < TGEN; tg++) {
        u16* hB = hb[0];
        short8v bf0 = *(const short8v*)&hB[ln * HROW + lg * 8];
        short8v bf1 = *(const short8v*)&hB[ln * HROW + 32 + lg * 8];
        short8v bf2 = {};
        u32 g32 = 0;
        if (lg == 0) {
            g32 = gdsb[(tg << 4) | ln];
            bf2[0] = (short)(g32 & 0xffffu); bf2[1] = (short)(g32 >> 16);
        } else if (lg == 1) {
            union { uint4 u; short8v s; } cvt;
            cvt.u = *(const uint4*)&nring[tg & 31][ln][0];
            bf2 = cvt.s;
        }
        f32x4 acc0 = bias0, acc1 = bias1;
        acc0 = __builtin_amdgcn_mfma_f32_16x16x32_bf16(a00, bf0, acc0, 0, 0, 0);
        acc0 = __builtin_amdgcn_mfma_f32_16x16x32_bf16(a01, bf1, acc0, 0, 0, 0);
        acc0 = __builtin_amdgcn_mfma_f32_16x16x32_bf16(a02, bf2, acc0, 0, 0, 0);
        acc1 = __builtin_amdgcn_mfma_f32_16x16x32_bf16(a10, bf0, acc1, 0, 0, 0);
        acc1 = __builtin_amdgcn_mfma_f32_16x16x32_bf16(a11, bf1, acc1, 0, 0, 0);
        acc1 = __builtin_amdgcn_mfma_f32_16x16x32_bf16(a12, bf2, acc1, 0, 0, 0);
        if (mlpw) {
            f32x4 m0 = b1v;
            m0 = __builtin_amdgcn_mfma_f32_16x16x32_bf16(w1F0, bf0, m0, 0, 0, 0);
            m0 = __builtin_amdgcn_mfma_f32_16x16x32_bf16(w1F1, bf1, m0, 0, 0, 0);
            float mp = w2L[0] * tanh2(m0[0]) + w2L[1] * tanh2(m0[1])
                     + w2L[2] * tanh2(m0[2]) + w2L[3] * tanh2(m0[3]);
            mp += __shfl_xor(mp, 16);
            mp += __shfl_xor(mp, 32);
            if (lg == 0) zpl[(ln << 2) | (w - 4)] = mp;
        }
        // rolling ring refill: once per 16 steps, slots for tg+16..tg+31
        if (((tg & 15) == 0) && tg > 0 && tg <= 176 && tid < 256) {
            const int s = tid >> 4, b = tid & 15;
            const int t = HISTN + tg + 16 + s;
            u32 r0 = 0, r1 = 0, r2 = 0, r3 = 0;
            if (t < 256) {
                size_t base = ((size_t)blockIdx.x * NB + b) * S_NOISE + (size_t)t * 8;
                if (is_f32) {
                    const float* nf = (const float*)noise + base;
                    float4 a = *(const float4*)nf, bq = *(const float4*)(nf + 4);
                    r0 = (u32)f2b(a.x) | ((u32)f2b(a.y) << 16);
                    r1 = (u32)f2b(a.z) | ((u32)f2b(a.w) << 16);
                    r2 = (u32)f2b(bq.x) | ((u32)f2b(bq.y) << 16);
                    r3 = (u32)f2b(bq.z) | ((u32)f2b(bq.w) << 16);
                } else {
                    uint4 nv = *(const uint4*)((const u16*)noise + base);
                    r0 = nv.x; r1 = nv.y; r2 = nv.z; r3 = nv.w;
                }
            }
            u32* dst = (u32*)&nring[(tg + 16 + s) & 31][b][0];
            dst[0] = r0; dst[1] = r1; dst[2] = r2; dst[3] = r3;
        }
        sync_lds();   // B1: zpl visible, all h reads complete
        // ---- P2: head finish (replicated, bit-identical per batch) + gates ----
        f32x4 zr = *(const f32x4*)&zpl[ln << 2];
        float th = tanh2(b2vs + zr[0] + zr[1] + zr[2] + zr[3]);
        float dp = 24.0f * th;
        dist += dp;
#pragma unroll
        for (int q = 0; q < 4; q++) {
            acc0[q] += wd0[q] * dp + ws0[q] * dist;
            acc1[q] += wd1[q] * dp + ws1[q] * dist;
        }
        float h0 = cellh(acc0, cst0);
        float h1 = cellh(acc1, cst1);
        u32 hp = cvtpk(h0, h1);
        const int j0 = (w << 2) | lg;
        hB[ln * HROW + j0] = (u16)hp;
        hB[ln * HROW + j0 + 32] = (u16)(hp >> 16);
        if (tid < NB) {
            const int to = HISTN + tg;
            if (is_f32) {
                out_f[to * 3] = gdf0; out_f[to * 3 + 1] = gdf1; out_f[to * 3 + 2] = dp;
                if (tg + 1 < TGEN) { gdf0 = gd_f[(tg + 1) * 2]; gdf1 = gd_f[(tg + 1) * 2 + 1]; }
            } else {
                out_h[to * 3] = (u16)(g32 & 0xffffu);
                out_h[to * 3 + 1] = (u16)(g32 >> 16);
                out_h[to * 3 + 2] = f2b(dp);
            }
        }
        sync_lds();   // B2: h_t visible
    }
}

extern "C" void kernel_launch(void* const* d_in, const int* in_sizes, int n_in,
                              void* d_out, int out_size, void* d_ws, size_t ws_size,
                              hipStream_t stream) {
    (void)in_sizes; (void)n_in; (void)d_ws; (void)ws_size; (void)out_size;
    lstm_gen_kernel<<<512, 512, 0, stream>>>(
        d_in[0], d_in[1], d_in[2], d_in[3], d_in[4], d_in[5],
        d_in[6], d_in[7], d_in[8], d_in[9], d_in[10], d_out);
}

// Round 8
// 424.894 us; speedup vs baseline: 1.7427x; 1.0256x over previous
//
#include <hip/hip_runtime.h>
#include <stdint.h>

typedef unsigned short u16;
typedef unsigned int u32;
typedef __attribute__((ext_vector_type(8))) short short8v;   // 8 bf16 = 4 VGPRs
typedef __attribute__((ext_vector_type(4))) float f32x4;

#define NB 16      // batches per block -> 512 blocks -> 2 blocks/CU
#define HISTN 64
#define TGEN 193   // L+1

// strides (elements)
#define S_NOISE 2048   // 256*8
#define S_HIST  192    // 64*3
#define S_GAP   386    // 193*2
#define S_OUT   771    // 257*3

#define HROW 104       // h row stride (u16): bank-uniform for b128 reads
#define L2E  1.442695041f
#define L2E2 2.885390082f

__device__ __forceinline__ float b2f(u16 u) { return __uint_as_float(((u32)u) << 16); }
__device__ __forceinline__ u16 f2b(float f) {
    u32 u = __float_as_uint(f);
    u32 r = (u + 0x7fffu + ((u >> 16) & 1u)) >> 16;
    return (u16)r;
}
__device__ __forceinline__ float rcp_(float x) { return __builtin_amdgcn_rcpf(x); }
__device__ __forceinline__ float ex2(float x) { return __builtin_amdgcn_exp2f(x); }
// pack 2 f32 -> 2 bf16 (RNE); lo = a, hi = b
__device__ __forceinline__ u32 cvtpk(float a, float b) {
    u32 r; asm("v_cvt_pk_bf16_f32 %0, %1, %2" : "=v"(r) : "v"(a), "v"(b)); return r;
}
// tanh from prescaled arg s = 2*log2e*x  (NaN-safe at saturation)
__device__ __forceinline__ float tanh2(float s) {
    return __builtin_fmaf(-2.0f, rcp_(1.0f + ex2(s)), 1.0f);
}
// LSTM gate epilogue on prescaled pre-acts: a0,a1,a3 = -log2e*pre(i,f,o), a2 = 2log2e*pre(g)
__device__ __forceinline__ float cellh(const f32x4 a, float& c) {
    float iv = rcp_(1.0f + ex2(a[0]));
    float fv = rcp_(1.0f + ex2(a[1]));
    float gv = tanh2(a[2]);
    float ov = rcp_(1.0f + ex2(a[3]));
    c = __builtin_fmaf(fv, c, iv * gv);
    return ov * tanh2(L2E2 * c);
}
__device__ __forceinline__ float ldv(const void* p, int idx, bool f32) {
    return f32 ? ((const float*)p)[idx] : b2f(((const u16*)p)[idx]);
}
// LDS-only barrier: drain LDS ops; global prefetch rides across (no vmcnt drain)
__device__ __forceinline__ void sync_lds() {
    asm volatile("s_waitcnt lgkmcnt(0)" ::: "memory");
    __builtin_amdgcn_s_barrier();
}

extern "C" __global__ void __launch_bounds__(512, 4)
lstm_gen_kernel(const void* __restrict__ noise, const void* __restrict__ hist_x,
                const void* __restrict__ gap, const void* __restrict__ pW_ih,
                const void* __restrict__ pW_hh, const void* __restrict__ pb_ih,
                const void* __restrict__ pb_hh, const void* __restrict__ pW1,
                const void* __restrict__ pb1, const void* __restrict__ pW2,
                const void* __restrict__ pb2, void* __restrict__ out)
{
    __shared__ u16 hb[2][NB * HROW];       // double-buffered h, 6656 B
    __shared__ u16 cxs[HISTN][NB][16];     // cond x-fragment rows, 32768 B
    __shared__ u16 xr[32][NB][16];         // gen x ring (gd|0|noise), 16384 B
    __shared__ float zpl[NB * 4];          // MLP per-wave partials, 256 B
    __shared__ float dpd[NB];              // dist handoff cond->gen, 64 B

    const int tid = threadIdx.x;
    const int lane = tid & 63;
    const int w = tid >> 6;        // wave 0..7; owns units {8w+2lg+T}
    const int lg = lane >> 4;      // k-group / C-row group
    const int ln = lane & 15;      // A-row / batch column

    // ---- dtype detection (proven logic) ----
    bool is_f32 = false;
    {
        const u32* p = (const u32*)pW_hh;
        for (int i = 0; i < 64; i++) {
            u32 v = p[i];
            float a = b2f((u16)(v & 0xffffu));
            float bb = b2f((u16)(v >> 16));
            if (!(fabsf(a) <= 0.5f) || !(fabsf(bb) <= 0.5f)) is_f32 = true;
        }
    }

    float* hs = (float*)xr;   // prestage scratch: hist fp32 (12288 B <= 16384 B)

    // ======== prestage P1a: zero h, hist fp32 scratch, cond noise, hist->out ====
    for (int i = tid; i < NB * HROW; i += 512) ((u32*)hb)[i] = 0u;   // both buffers
    for (int i = tid; i < HISTN * NB * 3; i += 512) {
        int t = i / 48, r = i % 48, b = r / 3, k = r % 3;
        hs[i] = ldv(hist_x, ((size_t)blockIdx.x * NB + b) * S_HIST + t * 3 + k, is_f32);
    }
    for (int i = tid; i < HISTN * NB * 4; i += 512) {
        int t = i >> 6, r = i & 63, b = r >> 2, q = r & 3;
        size_t base = ((size_t)blockIdx.x * NB + b) * S_NOISE + t * 8;
        u32 v;
        if (is_f32) {
            const float* p = (const float*)noise + base + q * 2;
            v = (u32)f2b(p[0]) | ((u32)f2b(p[1]) << 16);
        } else v = ((const u32*)noise)[(base >> 1) + q];
        ((u32*)&cxs[t][b][8])[q] = v;
    }
    for (int i = tid; i < NB * HISTN * 3; i += 512) {   // exact hist -> out copy
        int b = i / 192, e = i % 192;
        size_t bt = (size_t)blockIdx.x * NB + b;
        if (is_f32) ((float*)out)[bt * S_OUT + e] = ((const float*)hist_x)[bt * S_HIST + e];
        else ((u16*)out)[bt * S_OUT + e] = ((const u16*)hist_x)[bt * S_HIST + e];
    }
    __syncthreads();

    // ======== prestage P1b: per-batch cumsum + cond-x pack (16 lanes) ========
    if (tid < NB) {
        float dd = 0.0f;
#pragma unroll 1
        for (int t = 0; t < HISTN; t++) {
            float x0 = hs[t * 48 + tid * 3 + 0];
            float x1 = hs[t * 48 + tid * 3 + 1];
            float x2 = hs[t * 48 + tid * 3 + 2];
            dd += x2;
            u16 dph = f2b(x2); u16 dpl = f2b(x2 - b2f(dph));
            u16 dsh = f2b(dd); u16 dsl = f2b(dd - b2f(dsh));
            u32* dst = (u32*)&cxs[t][tid][0];
            dst[0] = (u32)f2b(x0) | ((u32)f2b(x1) << 16);
            dst[1] = (u32)dph | ((u32)dpl << 16);
            dst[2] = (u32)dsh | ((u32)dsl << 16);
            dst[3] = (u32)dsh | ((u32)dph << 16);
        }
        dpd[tid] = dd;
    }
    __syncthreads();

    // ======== prestage P1c: gen x ring init (slots 0..31) ========
    {
        const int s = tid >> 4, b = tid & 15;   // 32 slots x 16 batches
        u32* row = (u32*)&xr[s][b][0];
        // gd for tg = s (0..31, all valid)
        size_t gbase = ((size_t)blockIdx.x * NB + b) * S_GAP + s * 2;
        u32 gv;
        if (is_f32) {
            const float* p = (const float*)gap + gbase;
            gv = (u32)f2b(p[0]) | ((u32)f2b(p[1]) << 16);
        } else gv = *(const u32*)((const u16*)gap + gbase);
        row[0] = gv; row[1] = 0u; row[2] = 0u; row[3] = 0u;
        // noise t = 64+s
        size_t nbase = ((size_t)blockIdx.x * NB + b) * S_NOISE + (size_t)(HISTN + s) * 8;
        u32 r0, r1, r2, r3;
        if (is_f32) {
            const float* nf = (const float*)noise + nbase;
            float4 a = *(const float4*)nf, bq = *(const float4*)(nf + 4);
            r0 = (u32)f2b(a.x) | ((u32)f2b(a.y) << 16);
            r1 = (u32)f2b(a.z) | ((u32)f2b(a.w) << 16);
            r2 = (u32)f2b(bq.x) | ((u32)f2b(bq.y) << 16);
            r3 = (u32)f2b(bq.z) | ((u32)f2b(bq.w) << 16);
        } else {
            uint4 nv = *(const uint4*)((const u16*)noise + nbase);
            r0 = nv.x; r1 = nv.y; r2 = nv.z; r3 = nv.w;
        }
        row[4] = r0; row[5] = r1; row[6] = r2; row[7] = r3;
    }

    // ---- persistent A fragments, PRESCALED, adjacent-unit permutation:
    // tile (w,T) covers units u = 8w + 2*(row>>2) + T, gate = row&3 ----
    short8v a00, a01, a02, a10, a11, a12;
#pragma unroll
    for (int T = 0; T < 2; T++) {
        const int u = (w << 3) | ((ln >> 2) << 1) | T;
        const int g = ln & 3;
        const int row = (g << 6) | u;
        const float rs = (g == 2) ? L2E2 : -L2E;
        float wdp = ldv(pW_ih, row * 12 + 2, is_f32) * rs;
        u16 wdph = f2b(wdp); u16 wdpl = f2b(wdp - b2f(wdph));
        float wds = ldv(pW_ih, row * 12 + 3, is_f32) * rs;
        u16 wdsh = f2b(wds); u16 wdsl = f2b(wds - b2f(wdsh));
        short8v f0, f1, f2;
#pragma unroll
        for (int e = 0; e < 8; e++) {
            const int c = lg * 8 + e;
            f0[e] = (short)f2b(ldv(pW_hh, row * 64 + c, is_f32) * rs);
            f1[e] = (short)f2b(ldv(pW_hh, row * 64 + 32 + c, is_f32) * rs);
            u16 v = 0;
            if (c == 0 || c == 1) v = f2b(ldv(pW_ih, row * 12 + c, is_f32) * rs);
            else if (c == 2 || c == 3) v = wdph;
            else if (c == 4 || c == 5) v = wdsh;
            else if (c == 6) v = wdsl;
            else if (c == 7) v = wdpl;
            else if (c >= 8 && c < 16) v = f2b(ldv(pW_ih, row * 12 + (c - 4), is_f32) * rs);
            f2[e] = (short)v;
        }
        if (T == 0) { a00 = f0; a01 = f1; a02 = f2; }
        else        { a10 = f0; a11 = f1; a12 = f2; }
    }

    // C-side: prescaled bias + dp/dist weight columns; unit u = 8w+2lg+T
    f32x4 bias0, bias1, wd0, wd1, ws0, ws1;
#pragma unroll
    for (int T = 0; T < 2; T++) {
        const int u = (w << 3) | (lg << 1) | T;
        f32x4 bv, dv, sv;
#pragma unroll
        for (int q = 0; q < 4; q++) {
            const int row = (q << 6) | u;
            const float qs = (q == 2) ? L2E2 : -L2E;
            bv[q] = (ldv(pb_ih, row, is_f32) + ldv(pb_hh, row, is_f32)) * qs;
            dv[q] = ldv(pW_ih, row * 12 + 2, is_f32) * qs;
            sv[q] = ldv(pW_ih, row * 12 + 3, is_f32) * qs;
        }
        if (T == 0) { bias0 = bv; wd0 = dv; ws0 = sv; }
        else        { bias1 = bv; wd1 = dv; ws1 = sv; }
    }

    // ---- MLP head fragments (waves 4..7), prescaled by 2log2e ----
    const bool mlpw = (w >= 4);
    short8v w1F0 = {}, w1F1 = {};
    f32x4 b1v = {0.f, 0.f, 0.f, 0.f};
    float w2L[4] = {0.f, 0.f, 0.f, 0.f};
    if (mlpw) {
        const int wp = w - 4;
        const int row1 = (wp << 4) | ln;
#pragma unroll
        for (int e = 0; e < 8; e++) {
            w1F0[e] = (short)f2b(ldv(pW1, row1 * 64 + lg * 8 + e, is_f32) * L2E2);
            w1F1[e] = (short)f2b(ldv(pW1, row1 * 64 + 32 + lg * 8 + e, is_f32) * L2E2);
        }
        const int rq = (wp << 4) | (lg << 2);
#pragma unroll
        for (int q = 0; q < 4; q++) {
            b1v[q] = ldv(pb1, rq + q, is_f32) * L2E2;
            w2L[q] = ldv(pW2, rq + q, is_f32) * L2E2;
        }
    }
    const float b2vs = ldv(pb2, 0, is_f32) * L2E2;

    // per-lane batch pointers (batch = ln)
    const size_t gb = (size_t)blockIdx.x * NB + (size_t)ln;
    const float* gd_f = (const float*)gap + gb * S_GAP;
    u16* out_h = (u16*)out + gb * S_OUT;
    float* out_f = (float*)out + gb * S_OUT;

    float cst0 = 0.f, cst1 = 0.f;
    int pc = 0;
    const int hoff = (w << 3) | (lg << 1);   // adjacent unit pair base
    __syncthreads();   // all prestage + fragments ready

    // ================= conditioning: 64 steps, ONE barrier each =================
#pragma unroll 1
    for (int t = 0; t < HISTN; t++) {
        const u16* hc = hb[pc];
        u16* hn = hb[pc ^ 1];
        short8v bf0 = *(const short8v*)&hc[ln * HROW + lg * 8];
        short8v bf1 = *(const short8v*)&hc[ln * HROW + 32 + lg * 8];
        short8v bf2 = {};
        if (lg < 2) bf2 = *(const short8v*)&cxs[t][ln][lg * 8];
        f32x4 acc0 = bias0, acc1 = bias1;
        acc0 = __builtin_amdgcn_mfma_f32_16x16x32_bf16(a00, bf0, acc0, 0, 0, 0);
        acc0 = __builtin_amdgcn_mfma_f32_16x16x32_bf16(a01, bf1, acc0, 0, 0, 0);
        acc0 = __builtin_amdgcn_mfma_f32_16x16x32_bf16(a02, bf2, acc0, 0, 0, 0);
        acc1 = __builtin_amdgcn_mfma_f32_16x16x32_bf16(a10, bf0, acc1, 0, 0, 0);
        acc1 = __builtin_amdgcn_mfma_f32_16x16x32_bf16(a11, bf1, acc1, 0, 0, 0);
        acc1 = __builtin_amdgcn_mfma_f32_16x16x32_bf16(a12, bf2, acc1, 0, 0, 0);
        float h0 = cellh(acc0, cst0);
        float h1 = cellh(acc1, cst1);
        *(u32*)&hn[ln * HROW + hoff] = cvtpk(h0, h1);   // adjacent units: one b32
        sync_lds();
        pc ^= 1;
    }
    // pc == 0; final h in hb[0]

    float dist = dpd[ln];          // replicated per-batch dist after cumsum
    float gdf0 = 0.f, gdf1 = 0.f;  // writer fp32 gd prefetch (exact out path)
    if (is_f32 && tid < NB) { gdf0 = gd_f[0]; gdf1 = gd_f[1]; }

    // ================= generation: 193 steps, TWO barriers =================
#pragma unroll 1
    for (int tg = 0; tg < TGEN; tg++) {
        u16* hB = hb[0];
        short8v bf0 = *(const short8v*)&hB[ln * HROW + lg * 8];
        short8v bf1 = *(const short8v*)&hB[ln * HROW + 32 + lg * 8];
        short8v bf2 = {};
        if (lg < 2) bf2 = *(const short8v*)&xr[tg & 31][ln][lg * 8];
        f32x4 acc0 = bias0, acc1 = bias1;
        acc0 = __builtin_amdgcn_mfma_f32_16x16x32_bf16(a00, bf0, acc0, 0, 0, 0);
        acc0 = __builtin_amdgcn_mfma_f32_16x16x32_bf16(a01, bf1, acc0, 0, 0, 0);
        acc0 = __builtin_amdgcn_mfma_f32_16x16x32_bf16(a02, bf2, acc0, 0, 0, 0);
        acc1 = __builtin_amdgcn_mfma_f32_16x16x32_bf16(a10, bf0, acc1, 0, 0, 0);
        acc1 = __builtin_amdgcn_mfma_f32_16x16x32_bf16(a11, bf1, acc1, 0, 0, 0);
        acc1 = __builtin_amdgcn_mfma_f32_16x16x32_bf16(a12, bf2, acc1, 0, 0, 0);
        if (mlpw) {
            f32x4 m0 = b1v;
            m0 = __builtin_amdgcn_mfma_f32_16x16x32_bf16(w1F0, bf0, m0, 0, 0, 0);
            m0 = __builtin_amdgcn_mfma_f32_16x16x32_bf16(w1F1, bf1, m0, 0, 0, 0);
            float mp = w2L[0] * tanh2(m0[0]) + w2L[1] * tanh2(m0[1])
                     + w2L[2] * tanh2(m0[2]) + w2L[3] * tanh2(m0[3]);
            mp += __shfl_xor(mp, 16);
            mp += __shfl_xor(mp, 32);
            if (lg == 0) zpl[(ln << 2) | (w - 4)] = mp;
        }
        // ring refill (waves 0..3): once per 16 steps, slots tg+16..tg+31
        if (((tg & 15) == 0) && tg > 0 && tg <= 176 && tid < 256) {
            const int s = tid >> 4, b = tid & 15;
            const int tga = tg + 16 + s;            // target gen step
            u32* row = (u32*)&xr[tga & 31][b][0];
            u32 gv = 0;
            if (tga < TGEN) {
                size_t gbase = ((size_t)blockIdx.x * NB + b) * S_GAP + tga * 2;
                if (is_f32) {
                    const float* p = (const float*)gap + gbase;
                    gv = (u32)f2b(p[0]) | ((u32)f2b(p[1]) << 16);
                } else gv = *(const u32*)((const u16*)gap + gbase);
            }
            row[0] = gv;
            u32 r0 = 0, r1 = 0, r2 = 0, r3 = 0;
            if (HISTN + tga < 256) {
                size_t nbase = ((size_t)blockIdx.x * NB + b) * S_NOISE + (size_t)(HISTN + tga) * 8;
                if (is_f32) {
                    const float* nf = (const float*)noise + nbase;
                    float4 a = *(const float4*)nf, bq = *(const float4*)(nf + 4);
                    r0 = (u32)f2b(a.x) | ((u32)f2b(a.y) << 16);
                    r1 = (u32)f2b(a.z) | ((u32)f2b(a.w) << 16);
                    r2 = (u32)f2b(bq.x) | ((u32)f2b(bq.y) << 16);
                    r3 = (u32)f2b(bq.z) | ((u32)f2b(bq.w) << 16);
                } else {
                    uint4 nv = *(const uint4*)((const u16*)noise + nbase);
                    r0 = nv.x; r1 = nv.y; r2 = nv.z; r3 = nv.w;
                }
            }
            row[4] = r0; row[5] = r1; row[6] = r2; row[7] = r3;
        }
        sync_lds();   // B1: zpl visible, h reads complete
        // ---- P2: head finish (replicated) + dp/dist epilogue + gates ----
        f32x4 zr = *(const f32x4*)&zpl[ln << 2];
        float th = tanh2(b2vs + zr[0] + zr[1] + zr[2] + zr[3]);
        float dp = 24.0f * th;
        dist += dp;
#pragma unroll
        for (int q = 0; q < 4; q++) {
            acc0[q] = __builtin_fmaf(wd0[q], dp, __builtin_fmaf(ws0[q], dist, acc0[q]));
            acc1[q] = __builtin_fmaf(wd1[q], dp, __builtin_fmaf(ws1[q], dist, acc1[q]));
        }
        float h0 = cellh(acc0, cst0);
        float h1 = cellh(acc1, cst1);
        *(u32*)&hB[ln * HROW + hoff] = cvtpk(h0, h1);
        if (tid < NB) {
            const int to = HISTN + tg;
            if (is_f32) {
                out_f[to * 3] = gdf0; out_f[to * 3 + 1] = gdf1; out_f[to * 3 + 2] = dp;
                if (tg + 1 < TGEN) { gdf0 = gd_f[(tg + 1) * 2]; gdf1 = gd_f[(tg + 1) * 2 + 1]; }
            } else {
                u32 g32 = *(const u32*)&xr[tg & 31][ln][0];
                out_h[to * 3] = (u16)(g32 & 0xffffu);
                out_h[to * 3 + 1] = (u16)(g32 >> 16);
                out_h[to * 3 + 2] = f2b(dp);
            }
        }
        sync_lds();   // B2: h_t visible
    }
}

extern "C" void kernel_launch(void* const* d_in, const int* in_sizes, int n_in,
                              void* d_out, int out_size, void* d_ws, size_t ws_size,
                              hipStream_t stream) {
    (void)in_sizes; (void)n_in; (void)d_ws; (void)ws_size; (void)out_size;
    lstm_gen_kernel<<<512, 512, 0, stream>>>(
        d_in[0], d_in[1], d_in[2], d_in[3], d_in[4], d_in[5],
        d_in[6], d_in[7], d_in[8], d_in[9], d_in[10], d_out);
}